// Round 8
// baseline (1851.637 us; speedup 1.0000x reference)
//
#include <hip/hip_runtime.h>
#include <hip/hip_bf16.h>
#include <stdint.h>

typedef __bf16 bf16;
typedef __bf16 bf16x8 __attribute__((ext_vector_type(8)));
typedef float f32x4 __attribute__((ext_vector_type(4)));

typedef uint32_t __attribute__((address_space(1))) * gptr_as1;
typedef uint32_t __attribute__((address_space(3))) * lptr_as3;

__device__ __forceinline__ void async16(const void* g, void* l) {
    __builtin_amdgcn_global_load_lds((gptr_as1)(uintptr_t)g,
                                     (lptr_as3)(uintptr_t)l,
                                     16, 0, 0);
}

__device__ __forceinline__ void bar() {
    asm volatile("" ::: "memory");
    __builtin_amdgcn_s_barrier();
    asm volatile("" ::: "memory");
}

// ---------------------------------------------------------------- cvt f32->bf16
__global__ void cvt_f32_bf16_kernel(const float* __restrict__ src,
                                    bf16* __restrict__ dst, int n8) {
    int i = blockIdx.x * blockDim.x + threadIdx.x;
    if (i >= n8) return;
    const float4* s = reinterpret_cast<const float4*>(src);
    float4 a = s[2 * (size_t)i], b = s[2 * (size_t)i + 1];
    bf16x8 v;
    v[0] = (bf16)a.x; v[1] = (bf16)a.y; v[2] = (bf16)a.z; v[3] = (bf16)a.w;
    v[4] = (bf16)b.x; v[5] = (bf16)b.y; v[6] = (bf16)b.z; v[7] = (bf16)b.w;
    *reinterpret_cast<bf16x8*>(dst + (size_t)i * 8) = v;
}

// cvt + 16-row interleave: src row r (of DHID) -> dst row (r/16)*32 + sel*16 + r%16.
__global__ void cvt_ilv_kernel(const float* __restrict__ src,
                               bf16* __restrict__ dst, int n8, int sel) {
    int i = blockIdx.x * blockDim.x + threadIdx.x;
    if (i >= n8) return;
    const int row = i >> 8;          // / 256  (DIN=2048 -> 256 chunks/row)
    const int c = i & 255;
    const int drow = ((row >> 4) << 5) + (sel << 4) + (row & 15);
    const float4* s = reinterpret_cast<const float4*>(src);
    float4 a = s[2 * (size_t)i], b = s[2 * (size_t)i + 1];
    bf16x8 v;
    v[0] = (bf16)a.x; v[1] = (bf16)a.y; v[2] = (bf16)a.z; v[3] = (bf16)a.w;
    v[4] = (bf16)b.x; v[5] = (bf16)b.y; v[6] = (bf16)b.z; v[7] = (bf16)b.w;
    *reinterpret_cast<bf16x8*>(dst + ((size_t)drow * 256 + c) * 8) = v;
}

// ---------------------------------------------------------------- 256x128 GEMM, 2 blocks/CU (TLP overlap)
// C = A[M,K] * B[N,K]^T. BM=256, BN=128, BK=64. 512 thr / 8 waves (4Mx2N),
// wave tile 64x64, acc[4][4] f32x4 = 64 regs/thread. ks-sequential operand
// reads cap live VGPR ~110 -> __launch_bounds__(512,4) -> 16 waves/CU =
// 2 BLOCKS/CU. LDS single-buffered 48KB (A[256][64]+B[128][64]); two blocks
// fit in 96KB. Schedule per K-tile is deliberately simple:
//   stage 6 gloads; vmcnt(0); bar; {ks=0: read 8 frags, 16 MFMA};
//   {ks=1: read 8 frags, 16 MFMA}; bar;
// The stage stall / read bursts of one block are hidden by the OTHER resident
// block's MFMA (m114 co-scheduling) — replaces 4 rounds of null intra-block
// scheduling. Swizzle lds_byte = row*128 + (colb ^ ((row&7)<<4)), proven
// conflict-free (R3: SQ_LDS_BANK_CONFLICT = 0); gload_lds dest linear,
// global source pre-swizzled (rule #21). Single buffer => stage-after-bar is
// WAR-safe (all reads lgkm-complete before each wave's MFMAs issue, which
// precede its barrier arrival).
// EPI=0: bf16(gelu(acc*s1)) | EPI=1: f32(acc*s1) | EPI=2: swiglu, 16-col interleave.
template <int EPI, int K>
__global__ __launch_bounds__(512, 4)
void gemm2b(const bf16* __restrict__ A, const bf16* __restrict__ B,
            void* __restrict__ Cout, const float* __restrict__ s1p,
            const float* __restrict__ s2p, int N, int ldh) {
    __shared__ __align__(16) char sm[49152];

    const int tid = threadIdx.x;
    const int w = tid >> 6, l = tid & 63;
    const int wr = w >> 1, wc = w & 1;   // 4x2 wave grid; wave tile 64x64

    const int gx = gridDim.x;            // N/128
    const int nwg = gx * (int)gridDim.y;
    const int orig = blockIdx.y * gx + blockIdx.x;
    const int wg = (orig & 7) * (nwg >> 3) + (orig >> 3);
    const int bm = wg / gx, bn = wg % gx;

    constexpr int NT = K / 64;

    f32x4 acc[4][4] = {};

    char* const bufA = sm;           // [256][64] bf16, 32KB
    char* const bufB = sm + 32768;   // [128][64] bf16, 16KB
    const int arow = bm * 256, brow = bn * 128;

    const int srow_in = l >> 3;
    const int scolb = ((l & 7) ^ srow_in) << 4;
    auto STAGE = [&](char* ldsT, const bf16* g, int grow0, int kt, int r0) {
        const int rr = r0 + w * 8 + srow_in;
        const char* gp = (const char*)(g + (size_t)(grow0 + rr) * K + kt * 64) + scolb;
        async16(gp, ldsT + r0 * 128 + w * 1024);
    };

    const int rlane = l & 15;
    const int chi = (l >> 4) << 4;
    auto FRAG = [&](const char* tb, int row, int ks) -> bf16x8 {
        const int cb = (ks * 64 + chi) ^ ((row & 7) << 4);
        return *reinterpret_cast<const bf16x8*>(tb + row * 128 + cb);
    };

#pragma unroll 1
    for (int kt = 0; kt < NT; ++kt) {
        STAGE(bufA, A, arow, kt, 0);   STAGE(bufA, A, arow, kt, 64);
        STAGE(bufA, A, arow, kt, 128); STAGE(bufA, A, arow, kt, 192);
        STAGE(bufB, B, brow, kt, 0);   STAGE(bufB, B, brow, kt, 64);
        asm volatile("s_waitcnt vmcnt(0)" ::: "memory");
        bar();
#pragma unroll
        for (int ks = 0; ks < 2; ++ks) {
            bf16x8 av[4], bv[4];
#pragma unroll
            for (int i = 0; i < 4; ++i)
                av[i] = FRAG(bufA, wr * 64 + i * 16 + rlane, ks);
#pragma unroll
            for (int j = 0; j < 4; ++j)
                bv[j] = FRAG(bufB, wc * 64 + j * 16 + rlane, ks);
            __builtin_amdgcn_s_setprio(1);
#pragma unroll
            for (int i = 0; i < 4; ++i)
#pragma unroll
                for (int j = 0; j < 4; ++j)
                    acc[i][j] = __builtin_amdgcn_mfma_f32_16x16x32_bf16(av[i], bv[j], acc[i][j], 0, 0, 0);
            __builtin_amdgcn_s_setprio(0);
        }
        bar();
    }

    const float s1 = s1p[0];
    const int r0 = bm * 256 + wr * 64 + ((l >> 4) << 2);
    if constexpr (EPI == 2) {
        const float s2 = s2p[0];
        // global col = bn*128 + wc*64 + j*16 + rlane; 16-col gate/value pairs:
        // out col = (4*bn + 2*wc + jp)*16 + rlane
        const int hcb = (bn * 4 + wc * 2) * 16 + rlane;
#pragma unroll
        for (int i = 0; i < 4; ++i)
#pragma unroll
            for (int jp = 0; jp < 2; ++jp)
#pragma unroll
                for (int q = 0; q < 4; ++q) {
                    float g = acc[i][2 * jp][q] * s1;
                    float v = acc[i][2 * jp + 1][q] * s2;
                    float sig = 1.0f / (1.0f + __expf(-g));
                    ((bf16*)Cout)[(size_t)(r0 + i * 16 + q) * ldh + hcb + jp * 16] =
                        (bf16)(g * sig * v);
                }
    } else {
        const int c0 = bn * 128 + wc * 64 + rlane;
#pragma unroll
        for (int i = 0; i < 4; ++i)
#pragma unroll
            for (int j = 0; j < 4; ++j)
#pragma unroll
                for (int q = 0; q < 4; ++q) {
                    float v = acc[i][j][q] * s1;
                    size_t idx = (size_t)(r0 + i * 16 + q) * N + (c0 + j * 16);
                    if constexpr (EPI == 0) {
                        float g = 0.5f * v * (1.0f + erff(v * 0.70710678118654752f));
                        ((bf16*)Cout)[idx] = (bf16)g;
                    } else {
                        ((float*)Cout)[idx] = v;
                    }
                }
    }
}

// ---------------------------------------------------------------- launch
extern "C" void kernel_launch(void* const* d_in, const int* in_sizes, int n_in,
                              void* d_out, int out_size, void* d_ws, size_t ws_size,
                              hipStream_t stream) {
    constexpr int NTOK = 8192, DIN = 2048, DHID = 8192;

    const float* x  = (const float*)d_in[0];
    const float* W1 = (const float*)d_in[1];
    const float* W2 = (const float*)d_in[2];
    const float* Wh = (const float*)d_in[3];
    const float* W3 = (const float*)d_in[4];
    const float* s1 = (const float*)d_in[5];
    const float* s2 = (const float*)d_in[6];
    const float* sh = (const float*)d_in[7];
    const float* s3 = (const float*)d_in[8];
    float* out = (float*)d_out;

    char* ws = (char*)d_ws;
    size_t off = 0;
    bf16* xb   = (bf16*)(ws + off); off += (size_t)NTOK * DIN * 2;
    bf16* w12b = (bf16*)(ws + off); off += (size_t)2 * DHID * DIN * 2;
    bf16* w3b  = (bf16*)(ws + off); off += (size_t)DIN * DHID * 2;
    bf16* whb  = (bf16*)(ws + off); off += (size_t)DHID * DHID * 2;
    bf16* h1   = (bf16*)(ws + off); off += (size_t)NTOK * DHID * 2;
    bf16* h2   = (bf16*)(ws + off); off += (size_t)NTOK * DHID * 2;
    if (ws_size < off) return;

    auto cvt = [&](const float* s, bf16* d, size_t n) {
        int n8 = (int)(n / 8);
        cvt_f32_bf16_kernel<<<(n8 + 255) / 256, 256, 0, stream>>>(s, d, n8);
    };
    cvt(x,  xb,  (size_t)NTOK * DIN);
    cvt(Wh, whb, (size_t)DHID * DHID);
    cvt(W3, w3b, (size_t)DIN * DHID);
    {
        int n8 = (int)((size_t)DHID * DIN / 8);
        cvt_ilv_kernel<<<(n8 + 255) / 256, 256, 0, stream>>>(W1, w12b, n8, 0);
        cvt_ilv_kernel<<<(n8 + 255) / 256, 256, 0, stream>>>(W2, w12b, n8, 1);
    }

    // GEMM1+2 fused: C[8192, 16384] over interleaved W12, SwiGLU epilogue -> h1
    gemm2b<2, DIN><<<dim3(2 * DHID / 128, NTOK / 256), 512, 0, stream>>>(
        xb, w12b, h1, s1, s2, 2 * DHID, DHID);
    // hidden GEMM + gelu -> h2
    gemm2b<0, DHID><<<dim3(DHID / 128, NTOK / 256), 512, 0, stream>>>(
        h1, whb, h2, sh, sh, DHID, DHID);
    // output GEMM -> out (f32)
    gemm2b<1, DHID><<<dim3(DIN / 128, NTOK / 256), 512, 0, stream>>>(
        h2, w3b, out, s3, s3, DIN, DIN);
}